// Round 12
// baseline (132.621 us; speedup 1.0000x reference)
//
#include <hip/hip_runtime.h>

typedef unsigned short u16;
typedef unsigned int u32;
typedef short short8 __attribute__((ext_vector_type(8)));
typedef float f32x4 __attribute__((ext_vector_type(4)));

#define NTOK 1024
#define TT 16384   // N*B*L tokens
#define DD 128
#define EPSV 1e-5f
#define ST 2097152 // TT*DD, elements per expert-slice (Q/O, O2)
#define STKV 4194304 // TT*256, elements per expert KV slice (K|V interleaved)

__device__ __forceinline__ u16 f2bf(float f) {
    u32 u = __float_as_uint(f);
    u += 0x7fffu + ((u >> 16) & 1u);
    return (u16)(u >> 16);
}
__device__ __forceinline__ u32 pack2(u16 a, u16 b) { return (u32)a | ((u32)b << 16); }
// cheap bf16-pair unpack: 1 VALU per element
__device__ __forceinline__ void up2(u32 w, float& lo, float& hi) {
    lo = __uint_as_float(w << 16);
    hi = __uint_as_float(w & 0xffff0000u);
}

// ---------------- fused prep: x->bf16 | weights->bf16 | FULL routing ----------------
// 256-thread blocks (no VGPR cap). [0,1024): cvt x ; [1024,1344): cvt weights ;
// block 1344: routing with 4 tokens/thread (logits streamed, shfl_up capacity scan).
__global__ __launch_bounds__(256) void k_prep(const float* __restrict__ x,
        const float* __restrict__ eWq, const float* __restrict__ eWk,
        const float* __restrict__ eWv, const float* __restrict__ eWo, const float* __restrict__ eW1,
        const float* __restrict__ mWq, const float* __restrict__ mWk, const float* __restrict__ mWv,
        const float* __restrict__ mWo, const float* __restrict__ mW2,
        const float* __restrict__ mm, const float* __restrict__ Wr, const float* __restrict__ br,
        const int* __restrict__ modix,
        u16* __restrict__ Xb, u16* __restrict__ Wb,
        float* __restrict__ mask8, float* __restrict__ comb8, float* __restrict__ cnt8,
        float* __restrict__ bnsum, float* __restrict__ bnsq, float* __restrict__ loss) {
    int bid = blockIdx.x; int tid = threadIdx.x;
    if (bid < 1024) {
        int i = bid * 256 + tid;
        const float4* p = (const float4*)x + (size_t)i * 2;
        float4 a = p[0], b = p[1];
        uint4 o;
        o.x = pack2(f2bf(a.x), f2bf(a.y));
        o.y = pack2(f2bf(a.z), f2bf(a.w));
        o.z = pack2(f2bf(b.x), f2bf(b.y));
        o.w = pack2(f2bf(b.z), f2bf(b.w));
        *((uint4*)Xb + i) = o;
        return;
    }
    if (bid < 1344) {
        int i = (bid - 1024) * 256 + tid;     // 81920 threads, 8 elems each
        int tns = i >> 13;
        int off = (i & 8191) * 8;
        const float* src;
        switch (tns) {
            case 0: src = eWq; break; case 1: src = eWk; break; case 2: src = eWv; break;
            case 3: src = eWo; break; case 4: src = eW1; break; case 5: src = mWq; break;
            case 6: src = mWk; break; case 7: src = mWv; break; case 8: src = mWo; break;
            default: src = mW2; break;
        }
        const float4* p = (const float4*)(src + off);
        float4 a = p[0], b = p[1];
        uint4 o;
        o.x = pack2(f2bf(a.x), f2bf(a.y));
        o.y = pack2(f2bf(a.z), f2bf(a.w));
        o.z = pack2(f2bf(b.x), f2bf(b.y));
        o.w = pack2(f2bf(b.z), f2bf(b.w));
        *(uint4*)(Wb + tns * 65536 + off) = o;
        return;
    }
    // ---------------- routing block: 256 threads x 4 tokens ----------------
    __shared__ int wsumLDS[4][4];
    __shared__ float red[16];
    int lane = tid & 63, wav = tid >> 6;
    if (tid < 16) red[tid] = 0.f;
#pragma unroll
    for (int q = 0; q < 4; q++) { bnsum[tid + q * 256] = 0.f; bnsq[tid + q * 256] = 0.f; }
    float g[4][4];
    u32 rb[4];
#pragma unroll
    for (int j = 0; j < 4; j++) {
        int n = tid * 4 + j;
        const float4* a  = (const float4*)(mm + (size_t)n * DD);
        const float4* w0 = (const float4*)(Wr);
        const float4* w1p = (const float4*)(Wr + DD);
        const float4* w2 = (const float4*)(Wr + 2 * DD);
        const float4* w3 = (const float4*)(Wr + 3 * DD);
        float s0 = 0.f, s1 = 0.f, s2 = 0.f, s3 = 0.f;
#pragma unroll
        for (int jj = 0; jj < 32; jj++) {
            float4 av = a[jj];
            float4 v0 = w0[jj], v1 = w1p[jj], v2 = w2[jj], v3 = w3[jj];
            s0 += av.x * v0.x + av.y * v0.y + av.z * v0.z + av.w * v0.w;
            s1 += av.x * v1.x + av.y * v1.y + av.z * v1.z + av.w * v1.w;
            s2 += av.x * v2.x + av.y * v2.y + av.z * v2.z + av.w * v2.w;
            s3 += av.x * v3.x + av.y * v3.y + av.z * v3.z + av.w * v3.w;
        }
        float gg[4] = { s0 + br[0], s1 + br[1], s2 + br[2], s3 + br[3] };
        float mx = fmaxf(fmaxf(gg[0], gg[1]), fmaxf(gg[2], gg[3]));
        float ss = 0.f;
#pragma unroll
        for (int e = 0; e < 4; e++) { gg[e] = expf(gg[e] - mx); ss += gg[e]; }
        float inv = 1.f / ss;
#pragma unroll
        for (int e = 0; e < 4; e++) gg[e] *= inv;
        int i0 = 0; float b0 = gg[0];
#pragma unroll
        for (int e = 1; e < 4; e++) if (gg[e] > b0) { b0 = gg[e]; i0 = e; }
        int i1 = -1; float b1v = -1e30f;
#pragma unroll
        for (int e = 0; e < 4; e++) if (e != i0 && gg[e] > b1v) { b1v = gg[e]; i1 = e; }
        rb[j] = (1u << i0) | (1u << i1);
#pragma unroll
        for (int e = 0; e < 4; e++) g[j][e] = gg[e];
    }
    // per-expert within-thread inclusive counts + lane scan + cross-wave scan
    int cnt[4], loc[4][4];
#pragma unroll
    for (int e = 0; e < 4; e++) {
        int cc = 0;
#pragma unroll
        for (int j = 0; j < 4; j++) { cc += (rb[j] >> e) & 1; loc[e][j] = cc; }
        cnt[e] = cc;
    }
    int base[4];
#pragma unroll
    for (int e = 0; e < 4; e++) {
        int v = cnt[e];
        for (int off = 1; off < 64; off <<= 1) {
            int y = __shfl_up(v, off, 64);
            if (lane >= off) v += y;
        }
        if (lane == 63) wsumLDS[e][wav] = v;
        base[e] = v - cnt[e];           // exclusive-before-thread within wave
    }
    __syncthreads();
#pragma unroll
    for (int e = 0; e < 4; e++) {
        int o = 0;
        for (int w = 0; w < 4; w++) if (w < wav) o += wsumLDS[e][w];
        base[e] += o;
    }
    float sums[16];
#pragma unroll
    for (int q = 0; q < 16; q++) sums[q] = 0.f;
#pragma unroll
    for (int j = 0; j < 4; j++) {
        int n = tid * 4 + j;
        float rp[4]; float rsum = 0.f;
#pragma unroll
        for (int e = 0; e < 4; e++) {
            int bit = (rb[j] >> e) & 1;
            bool keep = (base[e] + loc[e][j]) <= 256;   // inclusive cumsum <= N/E
            rp[e] = (bit && keep) ? g[j][e] : 0.f;
            rsum += rp[e];
        }
        bool active = rsum > 0.f;
        int j0 = 0; float c0 = rp[0];
#pragma unroll
        for (int e = 1; e < 4; e++) if (rp[e] > c0) { c0 = rp[e]; j0 = e; }
        int j1 = -1; float c1 = -1e30f;
#pragma unroll
        for (int e = 0; e < 4; e++) if (e != j0 && rp[e] > c1) { c1 = rp[e]; j1 = e; }
#pragma unroll
        for (int e = 0; e < 4; e++) {
            bool sel = active && (e == j0 || e == j1);
            float mf = sel ? 1.f : 0.f;
            mask8[e * NTOK + n] = mf;
            comb8[e * NTOK + n] = rp[e];
            sums[e] += mf;
        }
#pragma unroll
        for (int mmod = 0; mmod < 4; mmod++) {
            float mf = (modix[n * 4 + mmod] == 1) ? 1.f : 0.f;
            mask8[(4 + mmod) * NTOK + n] = mf;
            comb8[(4 + mmod) * NTOK + n] = 0.25f * mf;   // mod_out / Mn folded in
            sums[4 + mmod] += mf;
        }
#pragma unroll
        for (int e = 0; e < 4; e++) sums[8 + e] += (float)((rb[j] >> e) & 1);
#pragma unroll
        for (int e = 0; e < 4; e++) sums[12 + e] += g[j][e];
    }
#pragma unroll
    for (int q = 0; q < 16; q++) {
        float v = sums[q];
        for (int off = 32; off; off >>= 1) v += __shfl_down(v, off, 64);
        if (lane == 0) atomicAdd(&red[q], v);
    }
    __syncthreads();
    if (tid == 0) {
        for (int c = 0; c < 8; c++) cnt8[c] = fmaxf(16.f * red[c], 1.f);
        float l = 0.f;
        for (int e = 0; e < 4; e++) l += (red[8 + e] / 1024.f) * (red[12 + e] / 1024.f);
        loss[0] = 4.f * l;
    }
}

// ---------------- batched QKV projection: grid (256 bm, 8 c); K/V interleaved per token ----
__global__ __launch_bounds__(256) void k_gemm_qkv(const u16* __restrict__ Xb, const u16* __restrict__ Wb,
        const float* __restrict__ ebq, const float* __restrict__ mbq,
        const float* __restrict__ mask8,
        u16* __restrict__ Qb, u16* __restrict__ KVb) {
    __shared__ u16 As[64 * 128];
    __shared__ u16 Bs[128 * 128];
    int tid = threadIdx.x; int bm = blockIdx.x; int c = blockIdx.y;
    int wq = (c < 4) ? c : 20 + (c - 4);
    int wk = (c < 4) ? 4 + c : 24 + (c - 4);
    int wv = (c < 4) ? 8 + c : 28 + (c - 4);
    const u16* Wsl[3] = { Wb + wq * 16384, Wb + wk * 16384, Wb + wv * 16384 };
    const float* bq = (c < 4) ? (ebq + c * 128) : (mbq + (c - 4) * 128);
    const float* maskp = mask8 + c * NTOK;
    bool qact = (maskp[bm * 4] != 0.f) || (maskp[bm * 4 + 1] != 0.f) ||
                (maskp[bm * 4 + 2] != 0.f) || (maskp[bm * 4 + 3] != 0.f);
    u16* Qc  = Qb + (size_t)c * ST;
    u16* KVc = KVb + (size_t)c * STKV;

    const uint4* asrc = (const uint4*)(Xb + (size_t)bm * 8192);
#pragma unroll
    for (int it = 0; it < 4; ++it) {
        int ci = it * 256 + tid;
        uint4 v = asrc[ci];
        int byte = ci * 16; int row = byte >> 8;
        *(uint4*)((char*)As + (byte ^ ((row & 7) << 4))) = v;
    }
    __syncthreads();
    int lane = tid & 63, wid = tid >> 6, lr = lane & 15, lg = lane >> 4;
    short8 a[4];
#pragma unroll
    for (int ks = 0; ks < 4; ++ks) {
        int kk = ks * 64 + lg * 16;
        int arow = wid * 16 + lr;
        a[ks] = *(const short8*)((const char*)As + ((arow * 256 + kk) ^ ((arow & 7) << 4)));
    }
    for (int y = 0; y < 3; ++y) {
        if (y == 0 && !qact) continue;   // Q only read for masked tokens (block-uniform skip)
        const uint4* wsrc = (const uint4*)Wsl[y];
#pragma unroll
        for (int it = 0; it < 8; ++it) {
            int qi = it * 256 + tid;
            uint4 v = wsrc[qi];
            int eo = qi * 8; int row = eo >> 7; int byte = eo * 2;
            *(uint4*)((char*)Bs + (byte ^ ((row & 7) << 4))) = v;
        }
        __syncthreads();
        f32x4 acc[8] = {};
#pragma unroll
        for (int ks = 0; ks < 4; ++ks) {
            int kk = ks * 64 + lg * 16;
#pragma unroll
            for (int nc = 0; nc < 8; ++nc) {
                int brow = nc * 16 + lr;
                short8 b = *(const short8*)((const char*)Bs + ((brow * 256 + kk) ^ ((brow & 7) << 4)));
                acc[nc] = __builtin_amdgcn_mfma_f32_16x16x32_bf16(a[ks], b, acc[nc], 0, 0, 0);
            }
        }
        int row0 = bm * 64 + wid * 16 + lg * 4;
#pragma unroll
        for (int nc = 0; nc < 8; ++nc) {
            int col = nc * 16 + lr;
            float bb = (y == 0) ? bq[col] : 0.f;
#pragma unroll
            for (int r = 0; r < 4; r++) {
                u16 hv = f2bf(acc[nc][r] + bb);
                if (y == 0) Qc[(size_t)(row0 + r) * 128 + col] = hv;
                else KVc[(size_t)(row0 + r) * 256 + (y == 2 ? 128 : 0) + col] = hv;
            }
        }
        __syncthreads();
    }
}

// ---------------- gather attention: single-pass online softmax, K+V loads paired --------
// grid 4096 linear, c = bid&7 (XCD pin); wave-uniform n mask skip. Ob aliases Qb slice.
__global__ __launch_bounds__(256) void k_attn(const u16* Qb, const u16* __restrict__ KVb,
        const float* __restrict__ tkv, const int* __restrict__ idx,
        const float* __restrict__ ebk, const float* __restrict__ ebv,
        const float* __restrict__ mbk, const float* __restrict__ mbv,
        const float* __restrict__ mask8, u16* Ob) {
    int bid = blockIdx.x;
    int c = bid & 7, inner = bid >> 3;     // expert -> XCD pinning (round-robin dispatch)
    int tid = threadIdx.x;
    int gid = inner * 256 + tid;
    int t = gid >> 3, h = gid & 7;
    int n = __builtin_amdgcn_readfirstlane(t >> 4);   // wave spans 8 consecutive t, same n
    int bl = t & 15;
    if (mask8[c * NTOK + n] == 0.f) return;           // wave-uniform skip
    // early vectorized loads of idx/tkv rows (wave-uniform address, cache-broadcast)
    const int4* ip = (const int4*)(idx + n * 16);
    int4 iv0 = ip[0], iv1 = ip[1], iv2 = ip[2], iv3 = ip[3];
    const float4* tp = (const float4*)(tkv + n * 16);
    float4 tv0 = tp[0], tv1 = tp[1], tv2 = tp[2], tv3 = tp[3];
    const u16* Qc = Qb + (size_t)c * ST;
    const u16* KVc = KVb + (size_t)c * STKV;
    u16* Oc = Ob + (size_t)c * ST;
    const float* bk = (c < 4) ? (ebk + c * 128) : (mbk + (c - 4) * 128);
    const float* bv = (c < 4) ? (ebv + c * 128) : (mbv + (c - 4) * 128);
    float qv[16];
    {
        const uint4* qp = (const uint4*)(Qc + (size_t)t * 128 + h * 16);
        uint4 a = qp[0], b = qp[1];
        up2(a.x, qv[0], qv[1]);   up2(a.y, qv[2], qv[3]);
        up2(a.z, qv[4], qv[5]);   up2(a.w, qv[6], qv[7]);
        up2(b.x, qv[8], qv[9]);   up2(b.y, qv[10], qv[11]);
        up2(b.z, qv[12], qv[13]); up2(b.w, qv[14], qv[15]);
    }
    float qb = 0.f;
#pragma unroll
    for (int i = 0; i < 16; i++) qb += qv[i] * bk[h * 16 + i];
    int gsav[16] = { iv0.x, iv0.y, iv0.z, iv0.w, iv1.x, iv1.y, iv1.z, iv1.w,
                     iv2.x, iv2.y, iv2.z, iv2.w, iv3.x, iv3.y, iv3.z, iv3.w };
    float tsav[16] = { tv0.x, tv0.y, tv0.z, tv0.w, tv1.x, tv1.y, tv1.z, tv1.w,
                       tv2.x, tv2.y, tv2.z, tv2.w, tv3.x, tv3.y, tv3.z, tv3.w };
    float m = -1e30f, l = 0.f;
    float o[16];
#pragma unroll
    for (int i = 0; i < 16; i++) o[i] = 0.f;
#pragma unroll 2
    for (int k = 0; k < 16; k++) {
        const u16* basep = KVc + (size_t)(gsav[k] * 16 + bl) * 256 + h * 16;
        const uint4* kp = (const uint4*)basep;
        const uint4* vp = (const uint4*)(basep + 128);
        uint4 ka = kp[0], kb2 = kp[1];
        uint4 va = vp[0], vb2 = vp[1];       // K and V issue together (adjacent 256B)
        float d0 = 0.f, d1 = 0.f, lo, hi;
        up2(ka.x, lo, hi);  d0 = fmaf(lo, qv[0], d0);  d1 = fmaf(hi, qv[1], d1);
        up2(ka.y, lo, hi);  d0 = fmaf(lo, qv[2], d0);  d1 = fmaf(hi, qv[3], d1);
        up2(ka.z, lo, hi);  d0 = fmaf(lo, qv[4], d0);  d1 = fmaf(hi, qv[5], d1);
        up2(ka.w, lo, hi);  d0 = fmaf(lo, qv[6], d0);  d1 = fmaf(hi, qv[7], d1);
        up2(kb2.x, lo, hi); d0 = fmaf(lo, qv[8], d0);  d1 = fmaf(hi, qv[9], d1);
        up2(kb2.y, lo, hi); d0 = fmaf(lo, qv[10], d0); d1 = fmaf(hi, qv[11], d1);
        up2(kb2.z, lo, hi); d0 = fmaf(lo, qv[12], d0); d1 = fmaf(hi, qv[13], d1);
        up2(kb2.w, lo, hi); d0 = fmaf(lo, qv[14], d0); d1 = fmaf(hi, qv[15], d1);
        float sv = 0.25f * (tsav[k] * (d0 + d1) + qb);   // k = tkv*kx + bk ; 1/sqrt(dh)=0.25
        float nm = fmaxf(m, sv);
        float scale = __expf(m - nm);        // 1 if m unchanged; 0 on first iter
        float e = __expf(sv - nm);
        m = nm;
        l = fmaf(l, scale, e);
        float cc = e * tsav[k];
        up2(va.x, lo, hi);  o[0] = fmaf(o[0], scale, cc * lo);   o[1] = fmaf(o[1], scale, cc * hi);
        up2(va.y, lo, hi);  o[2] = fmaf(o[2], scale, cc * lo);   o[3] = fmaf(o[3], scale, cc * hi);
        up2(va.z, lo, hi);  o[4] = fmaf(o[4], scale, cc * lo);   o[5] = fmaf(o[5], scale, cc * hi);
        up2(va.w, lo, hi);  o[6] = fmaf(o[6], scale, cc * lo);   o[7] = fmaf(o[7], scale, cc * hi);
        up2(vb2.x, lo, hi); o[8] = fmaf(o[8], scale, cc * lo);   o[9] = fmaf(o[9], scale, cc * hi);
        up2(vb2.y, lo, hi); o[10] = fmaf(o[10], scale, cc * lo); o[11] = fmaf(o[11], scale, cc * hi);
        up2(vb2.z, lo, hi); o[12] = fmaf(o[12], scale, cc * lo); o[13] = fmaf(o[13], scale, cc * hi);
        up2(vb2.w, lo, hi); o[14] = fmaf(o[14], scale, cc * lo); o[15] = fmaf(o[15], scale, cc * hi);
    }
    float inv = 1.f / l;
#pragma unroll
    for (int i = 0; i < 16; i++) o[i] = fmaf(o[i], inv, bv[h * 16 + i]);   // sum(attn)=1
    uint4 s0, s1;
    s0.x = pack2(f2bf(o[0]), f2bf(o[1]));  s0.y = pack2(f2bf(o[2]), f2bf(o[3]));
    s0.z = pack2(f2bf(o[4]), f2bf(o[5]));  s0.w = pack2(f2bf(o[6]), f2bf(o[7]));
    s1.x = pack2(f2bf(o[8]), f2bf(o[9]));  s1.y = pack2(f2bf(o[10]), f2bf(o[11]));
    s1.z = pack2(f2bf(o[12]), f2bf(o[13])); s1.w = pack2(f2bf(o[14]), f2bf(o[15]));
    uint4* op = (uint4*)(Oc + (size_t)t * 128 + h * 16);
    op[0] = s0; op[1] = s1;
}

// ---------------- O @ Wo.T + bo with masked BN stats; block skip; bf16 O2: grid (256,8) ----
__global__ __launch_bounds__(256) void k_gemm_o(const u16* __restrict__ Ab, const u16* __restrict__ Wb,
        const float* __restrict__ ebo, const float* __restrict__ mbo,
        u16* __restrict__ O2, const float* __restrict__ mask8,
        float* __restrict__ bnsum, float* __restrict__ bnsq) {
    __shared__ u16 As[64 * 128];
    __shared__ u16 Bs[128 * 128];
    __shared__ float ssum[128], ssq[128];
    int tid = threadIdx.x; int bm = blockIdx.x; int c = blockIdx.y;
    const float* maskp = mask8 + c * NTOK;
    // whole-block skip: all 4 tokens masked out => O2 never consumed, no stats
    if (maskp[bm * 4] == 0.f && maskp[bm * 4 + 1] == 0.f &&
        maskp[bm * 4 + 2] == 0.f && maskp[bm * 4 + 3] == 0.f) return;
    int wo = (c < 4) ? 12 + c : 32 + (c - 4);
    const u16* Wp = Wb + wo * 16384;
    const float* bo = (c < 4) ? (ebo + c * 128) : (mbo + (c - 4) * 128);
    if (tid < 128) { ssum[tid] = 0.f; ssq[tid] = 0.f; }
    const uint4* asrc = (const uint4*)(Ab + (size_t)c * ST + (size_t)bm * 8192);
#pragma unroll
    for (int it = 0; it < 4; ++it) {
        int ci = it * 256 + tid;
        uint4 v = asrc[ci];
        int byte = ci * 16; int row = byte >> 8;
        *(uint4*)((char*)As + (byte ^ ((row & 7) << 4))) = v;
    }
    const uint4* wsrc = (const uint4*)Wp;
#pragma unroll
    for (int it = 0; it < 8; ++it) {
        int qi = it * 256 + tid;
        uint4 v = wsrc[qi];
        int eo = qi * 8; int row = eo >> 7; int byte = eo * 2;
        *(uint4*)((char*)Bs + (byte ^ ((row & 7) << 4))) = v;
    }
    __syncthreads();
    int lane = tid & 63, wid = tid >> 6, lr = lane & 15, lg = lane >> 4;
    f32x4 acc[8] = {};
#pragma unroll
    for (int ks = 0; ks < 4; ++ks) {
        int kk = ks * 64 + lg * 16;
        int arow = wid * 16 + lr;
        short8 a = *(const short8*)((const char*)As + ((arow * 256 + kk) ^ ((arow & 7) << 4)));
#pragma unroll
        for (int nc = 0; nc < 8; ++nc) {
            int brow = nc * 16 + lr;
            short8 b = *(const short8*)((const char*)Bs + ((brow * 256 + kk) ^ ((brow & 7) << 4)));
            acc[nc] = __builtin_amdgcn_mfma_f32_16x16x32_bf16(a, b, acc[nc], 0, 0, 0);
        }
    }
    int nidx = bm * 4 + wid;
    float mk = maskp[nidx];
    int row0 = bm * 64 + wid * 16 + lg * 4;
    u16* O2c = O2 + (size_t)c * ST;
    float ps[8], pq[8];
#pragma unroll
    for (int nc = 0; nc < 8; ++nc) {
        int col = nc * 16 + lr;
        float bb = bo[col];
        float sv = 0.f, qv = 0.f;
#pragma unroll
        for (int r = 0; r < 4; r++) {
            float v = acc[nc][r] + bb;
            if (mk != 0.f) O2c[(size_t)(row0 + r) * 128 + col] = f2bf(v);
            sv += v; qv += v * v;
        }
        ps[nc] = sv * mk; pq[nc] = qv * mk;
    }
#pragma unroll
    for (int nc = 0; nc < 8; ++nc) {
        ps[nc] += __shfl_xor(ps[nc], 16, 64); ps[nc] += __shfl_xor(ps[nc], 32, 64);
        pq[nc] += __shfl_xor(pq[nc], 16, 64); pq[nc] += __shfl_xor(pq[nc], 32, 64);
    }
    if (lane < 16) {
#pragma unroll
        for (int nc = 0; nc < 8; ++nc) {
            atomicAdd(&ssum[nc * 16 + lane], ps[nc]);
            atomicAdd(&ssq[nc * 16 + lane], pq[nc]);
        }
    }
    __syncthreads();
    if (tid < 128) { atomicAdd(&bnsum[c * 128 + tid], ssum[tid]); atomicAdd(&bnsq[c * 128 + tid], ssq[tid]); }
}

// ---------------- fused final GEMM over 8 experts, 512 threads (8 waves): grid 256 ----------
__global__ __launch_bounds__(512) void k_gemm_w1(const u16* __restrict__ O2, const u16* __restrict__ Xb,
        const u16* __restrict__ Wb, const float* __restrict__ eb1, const float* __restrict__ mb2,
        const float* __restrict__ eGamma, const float* __restrict__ mGamma,
        const float* __restrict__ eBeta, const float* __restrict__ mBeta,
        const float* __restrict__ comb8, const float* __restrict__ cnt8,
        const float* __restrict__ bnsum, const float* __restrict__ bnsq,
        float* __restrict__ out) {
    __shared__ u16 As[64 * 128];
    __shared__ u16 Bs[128 * 128];
    __shared__ float scall[8][128], shall[8][128];
    int tid = threadIdx.x; int bm = blockIdx.x;
    // BN scale/shift for all 8 experts
#pragma unroll
    for (int j = 0; j < 2; ++j) {
        int id = j * 512 + tid;
        int c = id >> 7, d = id & 127;
        float cnt = cnt8[c];
        float mean = bnsum[c * 128 + d] / cnt;
        float var = bnsq[c * 128 + d] / cnt - mean * mean;
        float rs = rsqrtf(var + EPSV);
        const float* ga = (c < 4) ? (eGamma + c * 128) : (mGamma + (c - 4) * 128);
        const float* be = (c < 4) ? (eBeta + c * 128) : (mBeta + (c - 4) * 128);
        float gg = ga[d];
        scall[c][d] = rs * gg;
        shall[c][d] = be[d] - mean * rs * gg;
    }
    __syncthreads();
    int lane = tid & 63, wid = tid >> 6, lr = lane & 15, lg = lane >> 4;
    int wm = wid & 3, wn = wid >> 2;        // 4 m-frags x 2 n-halves
    f32x4 acc[4] = {};
    const uint4* xsrc = (const uint4*)(Xb + (size_t)bm * 8192);
    for (int c = 0; c < 8; ++c) {
        float wc4[4];
        wc4[0] = comb8[c * NTOK + bm * 4];     wc4[1] = comb8[c * NTOK + bm * 4 + 1];
        wc4[2] = comb8[c * NTOK + bm * 4 + 2]; wc4[3] = comb8[c * NTOK + bm * 4 + 3];
        if (wc4[0] == 0.f && wc4[1] == 0.f && wc4[2] == 0.f && wc4[3] == 0.f) continue;
        int wsl = (c < 4) ? 16 + c : 36 + (c - 4);
        const u16* Wp = Wb + wsl * 16384;
        const uint4* osrc = (const uint4*)(O2 + (size_t)c * ST + (size_t)bm * 8192);
        // stage A = wc * (BN(O2) + x), bf16
#pragma unroll
        for (int it = 0; it < 2; ++it) {
            int qi = it * 512 + tid;
            int eo = qi * 8; int row = eo >> 7; int cb = eo & 127;
            float wc = wc4[row >> 4];
            uint4 ov = osrc[qi]; uint4 xv = xsrc[qi];
            float olo, ohi, xlo, xhi;
            uint4 hh;
            up2(ov.x, olo, ohi); up2(xv.x, xlo, xhi);
            hh.x = pack2(f2bf((olo * scall[c][cb] + shall[c][cb] + xlo) * wc),
                         f2bf((ohi * scall[c][cb + 1] + shall[c][cb + 1] + xhi) * wc));
            up2(ov.y, olo, ohi); up2(xv.y, xlo, xhi);
            hh.y = pack2(f2bf((olo * scall[c][cb + 2] + shall[c][cb + 2] + xlo) * wc),
                         f2bf((ohi * scall[c][cb + 3] + shall[c][cb + 3] + xhi) * wc));
            up2(ov.z, olo, ohi); up2(xv.z, xlo, xhi);
            hh.z = pack2(f2bf((olo * scall[c][cb + 4] + shall[c][cb + 4] + xlo) * wc),
                         f2bf((ohi * scall[c][cb + 5] + shall[c][cb + 5] + xhi) * wc));
            up2(ov.w, olo, ohi); up2(xv.w, xlo, xhi);
            hh.w = pack2(f2bf((olo * scall[c][cb + 6] + shall[c][cb + 6] + xlo) * wc),
                         f2bf((ohi * scall[c][cb + 7] + shall[c][cb + 7] + xhi) * wc));
            *(uint4*)((char*)As + ((eo * 2) ^ ((row & 7) << 4))) = hh;
        }
        const uint4* wsrc = (const uint4*)Wp;
#pragma unroll
        for (int it = 0; it < 4; ++it) {
            int qi = it * 512 + tid;
            uint4 v = wsrc[qi];
            int eo = qi * 8; int row = eo >> 7; int byte = eo * 2;
            *(uint4*)((char*)Bs + (byte ^ ((row & 7) << 4))) = v;
        }
        __syncthreads();
#pragma unroll
        for (int ks = 0; ks < 4; ++ks) {
            int kk = ks * 64 + lg * 16;
            int arow = wm * 16 + lr;
            short8 a = *(const short8*)((const char*)As + ((arow * 256 + kk) ^ ((arow & 7) << 4)));
#pragma unroll
            for (int nc = 0; nc < 4; ++nc) {
                int brow = wn * 64 + nc * 16 + lr;
                short8 b = *(const short8*)((const char*)Bs + ((brow * 256 + kk) ^ ((brow & 7) << 4)));
                acc[nc] = __builtin_amdgcn_mfma_f32_16x16x32_bf16(a, b, acc[nc], 0, 0, 0);
            }
        }
        __syncthreads();
    }
    // epilogue: add Sum_c wc*b1_c and write out once
    int nidx = bm * 4 + wm;
    int row0 = bm * 64 + wm * 16 + lg * 4;
    float wc8[8];
#pragma unroll
    for (int c = 0; c < 8; ++c) wc8[c] = comb8[c * NTOK + nidx];
#pragma unroll
    for (int nc = 0; nc < 4; ++nc) {
        int col = wn * 64 + nc * 16 + lr;
        float bias = 0.f;
#pragma unroll
        for (int c = 0; c < 8; ++c) {
            const float* b1 = (c < 4) ? (eb1 + c * 128) : (mb2 + (c - 4) * 128);
            bias += wc8[c] * b1[col];
        }
#pragma unroll
        for (int r = 0; r < 4; r++)
            out[(size_t)(row0 + r) * 128 + col] = acc[nc][r] + bias;
    }
}

extern "C" void kernel_launch(void* const* d_in, const int* in_sizes, int n_in,
                              void* d_out, int out_size, void* d_ws, size_t ws_size,
                              hipStream_t stream) {
    (void)in_sizes; (void)n_in; (void)ws_size; (void)out_size;
    const float* x    = (const float*)d_in[0];
    const float* mm   = (const float*)d_in[1];
    const float* tkv  = (const float*)d_in[2];
    const int*   idx  = (const int*)d_in[3];
    const int*   modi = (const int*)d_in[4];
    const float* Wr   = (const float*)d_in[5];
    const float* br   = (const float*)d_in[6];
    const float* eWq = (const float*)d_in[7],  *eWk = (const float*)d_in[8],  *eWv = (const float*)d_in[9];
    const float* eWo = (const float*)d_in[10], *eW1 = (const float*)d_in[11];
    const float* mWq = (const float*)d_in[12], *mWk = (const float*)d_in[13], *mWv = (const float*)d_in[14];
    const float* mWo = (const float*)d_in[15], *mW2 = (const float*)d_in[16];
    const float* ebq = (const float*)d_in[17], *ebk = (const float*)d_in[18], *ebv = (const float*)d_in[19];
    const float* ebo = (const float*)d_in[20], *eBeta = (const float*)d_in[21], *eb1 = (const float*)d_in[22];
    const float* mbq = (const float*)d_in[23], *mbk = (const float*)d_in[24], *mbv = (const float*)d_in[25];
    const float* mbo = (const float*)d_in[26], *mBeta = (const float*)d_in[27], *mb2 = (const float*)d_in[28];
    const float* eGamma = (const float*)d_in[29], *mGamma = (const float*)d_in[30];
    float* out = (float*)d_out;

    char* wsb = (char*)d_ws;
    const size_t MB = 1024 * 1024;
    u16* Xb  = (u16*)wsb;                       // 0..4 MB
    u16* Wb  = (u16*)(wsb + 4 * MB);            // 4..5.3 MB (40 x 16384 bf16)
    u16* Qb  = (u16*)(wsb + 8 * MB);            // 8..40 MB  (attn O in-place)
    u16* KVb = (u16*)(wsb + 40 * MB);           // 40..104 MB (8 x 8MB K|V interleaved)
    u16* O2  = (u16*)(wsb + 104 * MB);          // 104..136 MB (bf16)
    float* comb8 = (float*)(wsb + 136 * MB);    // [8][1024]
    float* mask8 = comb8 + 8192;                // [8][1024]
    float* cnt8  = mask8 + 8192;                // [8]
    float* bnsum = cnt8 + 16;                   // [8][128]
    float* bnsq  = bnsum + 1024;                // [8][128]

    k_prep<<<1345, 256, 0, stream>>>(x, eWq, eWk, eWv, eWo, eW1, mWq, mWk, mWv, mWo, mW2,
                                     mm, Wr, br, modi, Xb, Wb,
                                     mask8, comb8, cnt8, bnsum, bnsq, out + (size_t)TT * DD);
    k_gemm_qkv<<<dim3(256, 8), 256, 0, stream>>>(Xb, Wb, ebq, mbq, mask8, Qb, KVb);
    k_attn<<<4096, 256, 0, stream>>>(Qb, KVb, tkv, idx, ebk, ebv, mbk, mbv, mask8, Qb);
    k_gemm_o<<<dim3(256, 8), 256, 0, stream>>>(Qb, Wb, ebo, mbo, O2, mask8, bnsum, bnsq);
    k_gemm_w1<<<256, 512, 0, stream>>>(O2, Xb, Wb, eb1, mb2, eGamma, mGamma, eBeta, mBeta,
                                       comb8, cnt8, bnsum, bnsq, out);
}

// Round 13
// 118.257 us; speedup vs baseline: 1.1215x; 1.1215x over previous
//
#include <hip/hip_runtime.h>

typedef unsigned short u16;
typedef unsigned int u32;
typedef short short8 __attribute__((ext_vector_type(8)));
typedef float f32x4 __attribute__((ext_vector_type(4)));

#define NTOK 1024
#define TT 16384   // N*B*L tokens
#define DD 128
#define EPSV 1e-5f
#define ST 2097152 // TT*DD, elements per expert-slice (Q/O, O2)
#define STKV 4194304 // TT*256, elements per expert KV slice (K|V interleaved)

__device__ __forceinline__ u16 f2bf(float f) {
    u32 u = __float_as_uint(f);
    u += 0x7fffu + ((u >> 16) & 1u);
    return (u16)(u >> 16);
}
__device__ __forceinline__ u32 pack2(u16 a, u16 b) { return (u32)a | ((u32)b << 16); }
// cheap bf16-pair unpack: 1 VALU per element
__device__ __forceinline__ void up2(u32 w, float& lo, float& hi) {
    lo = __uint_as_float(w << 16);
    hi = __uint_as_float(w & 0xffff0000u);
}

// ---------------- fused prep: x->bf16 | weights->bf16 | router logits ----------------
// blocks [0,1024): cvt x ; [1024,1344): cvt weights ; [1344,1360): logits
__global__ __launch_bounds__(256) void k_prep(const float* __restrict__ x,
        const float* __restrict__ eWq, const float* __restrict__ eWk,
        const float* __restrict__ eWv, const float* __restrict__ eWo, const float* __restrict__ eW1,
        const float* __restrict__ mWq, const float* __restrict__ mWk, const float* __restrict__ mWv,
        const float* __restrict__ mWo, const float* __restrict__ mW2,
        const float* __restrict__ mm, const float* __restrict__ Wr, const float* __restrict__ br,
        u16* __restrict__ Xb, u16* __restrict__ Wb, float* __restrict__ logits) {
    int bid = blockIdx.x; int tid = threadIdx.x;
    if (bid < 1024) {
        int i = bid * 256 + tid;
        const float4* p = (const float4*)x + (size_t)i * 2;
        float4 a = p[0], b = p[1];
        uint4 o;
        o.x = pack2(f2bf(a.x), f2bf(a.y));
        o.y = pack2(f2bf(a.z), f2bf(a.w));
        o.z = pack2(f2bf(b.x), f2bf(b.y));
        o.w = pack2(f2bf(b.z), f2bf(b.w));
        *((uint4*)Xb + i) = o;
    } else if (bid < 1344) {
        int i = (bid - 1024) * 256 + tid;     // 81920 threads, 8 elems each
        int tns = i >> 13;
        int off = (i & 8191) * 8;
        const float* src;
        switch (tns) {
            case 0: src = eWq; break; case 1: src = eWk; break; case 2: src = eWv; break;
            case 3: src = eWo; break; case 4: src = eW1; break; case 5: src = mWq; break;
            case 6: src = mWk; break; case 7: src = mWv; break; case 8: src = mWo; break;
            default: src = mW2; break;
        }
        const float4* p = (const float4*)(src + off);
        float4 a = p[0], b = p[1];
        uint4 o;
        o.x = pack2(f2bf(a.x), f2bf(a.y));
        o.y = pack2(f2bf(a.z), f2bf(a.w));
        o.z = pack2(f2bf(b.x), f2bf(b.y));
        o.w = pack2(f2bf(b.z), f2bf(b.w));
        *(uint4*)(Wb + tns * 65536 + off) = o;
    } else {
        int i = (bid - 1344) * 256 + tid;     // 4096 = 1024 n * 4 e
        int n = i >> 2, e = i & 3;
        const float4* a = (const float4*)(mm + (size_t)n * DD);
        const float4* w = (const float4*)(Wr + (size_t)e * DD);
        float s = 0.f;
#pragma unroll
        for (int j = 0; j < 32; j++) {
            float4 av = a[j], wv = w[j];
            s += av.x * wv.x + av.y * wv.y + av.z * wv.z + av.w * wv.w;
        }
        logits[i] = s + br[e];
    }
}

// ---------------- routing: softmax, top2, capacity (ballot scan), masks, loss, zero stats ---
__global__ __launch_bounds__(1024) void k_route(const float* __restrict__ logits, const int* __restrict__ modix,
                                                float* __restrict__ mask8, float* __restrict__ comb8,
                                                float* __restrict__ cnt8, float* __restrict__ bnsum,
                                                float* __restrict__ bnsq, float* __restrict__ loss) {
    __shared__ int wsum[4][16];
    __shared__ float red[16];
    int n = threadIdx.x;
    if (n < 16) red[n] = 0.f;
    bnsum[n] = 0.f; bnsq[n] = 0.f;                      // zero [8][128] stats
    float g[4];
    float mx = -1e30f;
#pragma unroll
    for (int e = 0; e < 4; e++) { g[e] = logits[n * 4 + e]; mx = fmaxf(mx, g[e]); }
    float s = 0.f;
#pragma unroll
    for (int e = 0; e < 4; e++) { g[e] = expf(g[e] - mx); s += g[e]; }
    float inv = 1.f / s;
#pragma unroll
    for (int e = 0; e < 4; e++) g[e] *= inv;
    // top2 of gate (ties -> lower index, matching lax.top_k)
    int i0 = 0; float b0 = g[0];
#pragma unroll
    for (int e = 1; e < 4; e++) if (g[e] > b0) { b0 = g[e]; i0 = e; }
    int i1 = -1; float b1v = -1e30f;
#pragma unroll
    for (int e = 0; e < 4; e++) if (e != i0 && g[e] > b1v) { b1v = g[e]; i1 = e; }
    u32 rbits = (1u << i0) | (1u << i1);
    // inclusive cumsum per expert via wave ballot + cross-wave scan; keep iff <= N/E = 256
    int wav = n >> 6, lane = n & 63;
    unsigned long long lm = (~0ull) >> (63 - lane);     // bits 0..lane
    int pre[4];
#pragma unroll
    for (int e = 0; e < 4; e++) {
        unsigned long long m = __ballot((rbits >> e) & 1u);
        pre[e] = __popcll(m & lm);
        if (lane == 63) wsum[e][wav] = __popcll(m);
    }
    __syncthreads();
    float rp[4]; float rsum = 0.f;
#pragma unroll
    for (int e = 0; e < 4; e++) {
        int off = 0;
        for (int w = 0; w < 16; w++) if (w < wav) off += wsum[e][w];
        bool keep = (off + pre[e]) <= 256;
        rp[e] = (((rbits >> e) & 1u) && keep) ? g[e] : 0.f;
        rsum += rp[e];
    }
    bool active = rsum > 0.f;
    // top2 of rprobs (reproduce lax.top_k filler-index tie-break for the BN mask)
    int j0 = 0; float c0 = rp[0];
#pragma unroll
    for (int e = 1; e < 4; e++) if (rp[e] > c0) { c0 = rp[e]; j0 = e; }
    int j1 = -1; float c1 = -1e30f;
#pragma unroll
    for (int e = 0; e < 4; e++) if (e != j0 && rp[e] > c1) { c1 = rp[e]; j1 = e; }
    float vals[16];
#pragma unroll
    for (int e = 0; e < 4; e++) {
        bool sel = active && (e == j0 || e == j1);
        float mf = sel ? 1.f : 0.f;
        mask8[e * NTOK + n] = mf;
        comb8[e * NTOK + n] = rp[e];
        vals[e] = mf;
    }
#pragma unroll
    for (int m = 0; m < 4; m++) {
        float mf = (modix[n * 4 + m] == 1) ? 1.f : 0.f;
        mask8[(4 + m) * NTOK + n] = mf;
        comb8[(4 + m) * NTOK + n] = 0.25f * mf;         // mod_out / Mn folded in
        vals[4 + m] = mf;
    }
#pragma unroll
    for (int e = 0; e < 4; e++) vals[8 + e] = ((rbits >> e) & 1u) ? 1.f : 0.f;
#pragma unroll
    for (int e = 0; e < 4; e++) vals[12 + e] = g[e];
#pragma unroll
    for (int q = 0; q < 16; q++) {
        float v = vals[q];
        for (int off = 32; off; off >>= 1) v += __shfl_down(v, off, 64);
        if (lane == 0) atomicAdd(&red[q], v);
    }
    __syncthreads();
    if (n == 0) {
        for (int c = 0; c < 8; c++) cnt8[c] = fmaxf(16.f * red[c], 1.f);
        float l = 0.f;
        for (int e = 0; e < 4; e++) l += (red[8 + e] / 1024.f) * (red[12 + e] / 1024.f);
        loss[0] = 4.f * l;
    }
}

// ---------------- batched QKV projection: grid (256 bm, 8 c); K/V interleaved per token ----
__global__ __launch_bounds__(256) void k_gemm_qkv(const u16* __restrict__ Xb, const u16* __restrict__ Wb,
        const float* __restrict__ ebq, const float* __restrict__ mbq,
        const float* __restrict__ mask8,
        u16* __restrict__ Qb, u16* __restrict__ KVb) {
    __shared__ u16 As[64 * 128];
    __shared__ u16 Bs[128 * 128];
    int tid = threadIdx.x; int bm = blockIdx.x; int c = blockIdx.y;
    int wq = (c < 4) ? c : 20 + (c - 4);
    int wk = (c < 4) ? 4 + c : 24 + (c - 4);
    int wv = (c < 4) ? 8 + c : 28 + (c - 4);
    const u16* Wsl[3] = { Wb + wq * 16384, Wb + wk * 16384, Wb + wv * 16384 };
    const float* bq = (c < 4) ? (ebq + c * 128) : (mbq + (c - 4) * 128);
    const float* maskp = mask8 + c * NTOK;
    bool qact = (maskp[bm * 4] != 0.f) || (maskp[bm * 4 + 1] != 0.f) ||
                (maskp[bm * 4 + 2] != 0.f) || (maskp[bm * 4 + 3] != 0.f);
    u16* Qc  = Qb + (size_t)c * ST;
    u16* KVc = KVb + (size_t)c * STKV;

    const uint4* asrc = (const uint4*)(Xb + (size_t)bm * 8192);
#pragma unroll
    for (int it = 0; it < 4; ++it) {
        int ci = it * 256 + tid;
        uint4 v = asrc[ci];
        int byte = ci * 16; int row = byte >> 8;
        *(uint4*)((char*)As + (byte ^ ((row & 7) << 4))) = v;
    }
    __syncthreads();
    int lane = tid & 63, wid = tid >> 6, lr = lane & 15, lg = lane >> 4;
    short8 a[4];
#pragma unroll
    for (int ks = 0; ks < 4; ++ks) {
        int kk = ks * 64 + lg * 16;
        int arow = wid * 16 + lr;
        a[ks] = *(const short8*)((const char*)As + ((arow * 256 + kk) ^ ((arow & 7) << 4)));
    }
    for (int y = 0; y < 3; ++y) {
        if (y == 0 && !qact) continue;   // Q only read for masked tokens (block-uniform skip)
        const uint4* wsrc = (const uint4*)Wsl[y];
#pragma unroll
        for (int it = 0; it < 8; ++it) {
            int qi = it * 256 + tid;
            uint4 v = wsrc[qi];
            int eo = qi * 8; int row = eo >> 7; int byte = eo * 2;
            *(uint4*)((char*)Bs + (byte ^ ((row & 7) << 4))) = v;
        }
        __syncthreads();
        f32x4 acc[8] = {};
#pragma unroll
        for (int ks = 0; ks < 4; ++ks) {
            int kk = ks * 64 + lg * 16;
#pragma unroll
            for (int nc = 0; nc < 8; ++nc) {
                int brow = nc * 16 + lr;
                short8 b = *(const short8*)((const char*)Bs + ((brow * 256 + kk) ^ ((brow & 7) << 4)));
                acc[nc] = __builtin_amdgcn_mfma_f32_16x16x32_bf16(a[ks], b, acc[nc], 0, 0, 0);
            }
        }
        int row0 = bm * 64 + wid * 16 + lg * 4;
#pragma unroll
        for (int nc = 0; nc < 8; ++nc) {
            int col = nc * 16 + lr;
            float bb = (y == 0) ? bq[col] : 0.f;
#pragma unroll
            for (int r = 0; r < 4; r++) {
                u16 hv = f2bf(acc[nc][r] + bb);
                if (y == 0) Qc[(size_t)(row0 + r) * 128 + col] = hv;
                else KVc[(size_t)(row0 + r) * 256 + (y == 2 ? 128 : 0) + col] = hv;
            }
        }
        __syncthreads();
    }
}

// ---------------- gather attention: single-pass online softmax, K+V loads paired --------
// grid 4096 linear, c = bid&7 (XCD pin); wave-uniform n mask skip. Ob aliases Qb slice.
__global__ __launch_bounds__(256) void k_attn(const u16* Qb, const u16* __restrict__ KVb,
        const float* __restrict__ tkv, const int* __restrict__ idx,
        const float* __restrict__ ebk, const float* __restrict__ ebv,
        const float* __restrict__ mbk, const float* __restrict__ mbv,
        const float* __restrict__ mask8, u16* Ob) {
    int bid = blockIdx.x;
    int c = bid & 7, inner = bid >> 3;     // expert -> XCD pinning (round-robin dispatch)
    int tid = threadIdx.x;
    int gid = inner * 256 + tid;
    int t = gid >> 3, h = gid & 7;
    int n = __builtin_amdgcn_readfirstlane(t >> 4);   // wave spans 8 consecutive t, same n
    int bl = t & 15;
    if (mask8[c * NTOK + n] == 0.f) return;           // wave-uniform skip
    // early vectorized loads of idx/tkv rows (wave-uniform address, cache-broadcast)
    const int4* ip = (const int4*)(idx + n * 16);
    int4 iv0 = ip[0], iv1 = ip[1], iv2 = ip[2], iv3 = ip[3];
    const float4* tp = (const float4*)(tkv + n * 16);
    float4 tv0 = tp[0], tv1 = tp[1], tv2 = tp[2], tv3 = tp[3];
    const u16* Qc = Qb + (size_t)c * ST;
    const u16* KVc = KVb + (size_t)c * STKV;
    u16* Oc = Ob + (size_t)c * ST;
    const float* bk = (c < 4) ? (ebk + c * 128) : (mbk + (c - 4) * 128);
    const float* bv = (c < 4) ? (ebv + c * 128) : (mbv + (c - 4) * 128);
    float qv[16];
    {
        const uint4* qp = (const uint4*)(Qc + (size_t)t * 128 + h * 16);
        uint4 a = qp[0], b = qp[1];
        up2(a.x, qv[0], qv[1]);   up2(a.y, qv[2], qv[3]);
        up2(a.z, qv[4], qv[5]);   up2(a.w, qv[6], qv[7]);
        up2(b.x, qv[8], qv[9]);   up2(b.y, qv[10], qv[11]);
        up2(b.z, qv[12], qv[13]); up2(b.w, qv[14], qv[15]);
    }
    float qb = 0.f;
#pragma unroll
    for (int i = 0; i < 16; i++) qb += qv[i] * bk[h * 16 + i];
    int gsav[16] = { iv0.x, iv0.y, iv0.z, iv0.w, iv1.x, iv1.y, iv1.z, iv1.w,
                     iv2.x, iv2.y, iv2.z, iv2.w, iv3.x, iv3.y, iv3.z, iv3.w };
    float tsav[16] = { tv0.x, tv0.y, tv0.z, tv0.w, tv1.x, tv1.y, tv1.z, tv1.w,
                       tv2.x, tv2.y, tv2.z, tv2.w, tv3.x, tv3.y, tv3.z, tv3.w };
    float m = -1e30f, l = 0.f;
    float o[16];
#pragma unroll
    for (int i = 0; i < 16; i++) o[i] = 0.f;
#pragma unroll 2
    for (int k = 0; k < 16; k++) {
        const u16* basep = KVc + (size_t)(gsav[k] * 16 + bl) * 256 + h * 16;
        const uint4* kp = (const uint4*)basep;
        const uint4* vp = (const uint4*)(basep + 128);
        uint4 ka = kp[0], kb2 = kp[1];
        uint4 va = vp[0], vb2 = vp[1];       // K and V issue together (adjacent 256B)
        float d0 = 0.f, d1 = 0.f, lo, hi;
        up2(ka.x, lo, hi);  d0 = fmaf(lo, qv[0], d0);  d1 = fmaf(hi, qv[1], d1);
        up2(ka.y, lo, hi);  d0 = fmaf(lo, qv[2], d0);  d1 = fmaf(hi, qv[3], d1);
        up2(ka.z, lo, hi);  d0 = fmaf(lo, qv[4], d0);  d1 = fmaf(hi, qv[5], d1);
        up2(ka.w, lo, hi);  d0 = fmaf(lo, qv[6], d0);  d1 = fmaf(hi, qv[7], d1);
        up2(kb2.x, lo, hi); d0 = fmaf(lo, qv[8], d0);  d1 = fmaf(hi, qv[9], d1);
        up2(kb2.y, lo, hi); d0 = fmaf(lo, qv[10], d0); d1 = fmaf(hi, qv[11], d1);
        up2(kb2.z, lo, hi); d0 = fmaf(lo, qv[12], d0); d1 = fmaf(hi, qv[13], d1);
        up2(kb2.w, lo, hi); d0 = fmaf(lo, qv[14], d0); d1 = fmaf(hi, qv[15], d1);
        float sv = 0.25f * (tsav[k] * (d0 + d1) + qb);   // k = tkv*kx + bk ; 1/sqrt(dh)=0.25
        float nm = fmaxf(m, sv);
        float scale = __expf(m - nm);        // 1 if m unchanged; 0 on first iter
        float e = __expf(sv - nm);
        m = nm;
        l = fmaf(l, scale, e);
        float cc = e * tsav[k];
        up2(va.x, lo, hi);  o[0] = fmaf(o[0], scale, cc * lo);   o[1] = fmaf(o[1], scale, cc * hi);
        up2(va.y, lo, hi);  o[2] = fmaf(o[2], scale, cc * lo);   o[3] = fmaf(o[3], scale, cc * hi);
        up2(va.z, lo, hi);  o[4] = fmaf(o[4], scale, cc * lo);   o[5] = fmaf(o[5], scale, cc * hi);
        up2(va.w, lo, hi);  o[6] = fmaf(o[6], scale, cc * lo);   o[7] = fmaf(o[7], scale, cc * hi);
        up2(vb2.x, lo, hi); o[8] = fmaf(o[8], scale, cc * lo);   o[9] = fmaf(o[9], scale, cc * hi);
        up2(vb2.y, lo, hi); o[10] = fmaf(o[10], scale, cc * lo); o[11] = fmaf(o[11], scale, cc * hi);
        up2(vb2.z, lo, hi); o[12] = fmaf(o[12], scale, cc * lo); o[13] = fmaf(o[13], scale, cc * hi);
        up2(vb2.w, lo, hi); o[14] = fmaf(o[14], scale, cc * lo); o[15] = fmaf(o[15], scale, cc * hi);
    }
    float inv = 1.f / l;
#pragma unroll
    for (int i = 0; i < 16; i++) o[i] = fmaf(o[i], inv, bv[h * 16 + i]);   // sum(attn)=1
    uint4 s0, s1;
    s0.x = pack2(f2bf(o[0]), f2bf(o[1]));  s0.y = pack2(f2bf(o[2]), f2bf(o[3]));
    s0.z = pack2(f2bf(o[4]), f2bf(o[5]));  s0.w = pack2(f2bf(o[6]), f2bf(o[7]));
    s1.x = pack2(f2bf(o[8]), f2bf(o[9]));  s1.y = pack2(f2bf(o[10]), f2bf(o[11]));
    s1.z = pack2(f2bf(o[12]), f2bf(o[13])); s1.w = pack2(f2bf(o[14]), f2bf(o[15]));
    uint4* op = (uint4*)(Oc + (size_t)t * 128 + h * 16);
    op[0] = s0; op[1] = s1;
}

// ---------------- O @ Wo.T + bo with masked BN stats; block skip; bf16 O2: grid (256,8) ----
__global__ __launch_bounds__(256) void k_gemm_o(const u16* __restrict__ Ab, const u16* __restrict__ Wb,
        const float* __restrict__ ebo, const float* __restrict__ mbo,
        u16* __restrict__ O2, const float* __restrict__ mask8,
        float* __restrict__ bnsum, float* __restrict__ bnsq) {
    __shared__ u16 As[64 * 128];
    __shared__ u16 Bs[128 * 128];
    __shared__ float ssum[128], ssq[128];
    int tid = threadIdx.x; int bm = blockIdx.x; int c = blockIdx.y;
    const float* maskp = mask8 + c * NTOK;
    // whole-block skip: all 4 tokens masked out => O2 never consumed, no stats
    if (maskp[bm * 4] == 0.f && maskp[bm * 4 + 1] == 0.f &&
        maskp[bm * 4 + 2] == 0.f && maskp[bm * 4 + 3] == 0.f) return;
    int wo = (c < 4) ? 12 + c : 32 + (c - 4);
    const u16* Wp = Wb + wo * 16384;
    const float* bo = (c < 4) ? (ebo + c * 128) : (mbo + (c - 4) * 128);
    if (tid < 128) { ssum[tid] = 0.f; ssq[tid] = 0.f; }
    const uint4* asrc = (const uint4*)(Ab + (size_t)c * ST + (size_t)bm * 8192);
#pragma unroll
    for (int it = 0; it < 4; ++it) {
        int ci = it * 256 + tid;
        uint4 v = asrc[ci];
        int byte = ci * 16; int row = byte >> 8;
        *(uint4*)((char*)As + (byte ^ ((row & 7) << 4))) = v;
    }
    const uint4* wsrc = (const uint4*)Wp;
#pragma unroll
    for (int it = 0; it < 8; ++it) {
        int qi = it * 256 + tid;
        uint4 v = wsrc[qi];
        int eo = qi * 8; int row = eo >> 7; int byte = eo * 2;
        *(uint4*)((char*)Bs + (byte ^ ((row & 7) << 4))) = v;
    }
    __syncthreads();
    int lane = tid & 63, wid = tid >> 6, lr = lane & 15, lg = lane >> 4;
    f32x4 acc[8] = {};
#pragma unroll
    for (int ks = 0; ks < 4; ++ks) {
        int kk = ks * 64 + lg * 16;
        int arow = wid * 16 + lr;
        short8 a = *(const short8*)((const char*)As + ((arow * 256 + kk) ^ ((arow & 7) << 4)));
#pragma unroll
        for (int nc = 0; nc < 8; ++nc) {
            int brow = nc * 16 + lr;
            short8 b = *(const short8*)((const char*)Bs + ((brow * 256 + kk) ^ ((brow & 7) << 4)));
            acc[nc] = __builtin_amdgcn_mfma_f32_16x16x32_bf16(a, b, acc[nc], 0, 0, 0);
        }
    }
    int nidx = bm * 4 + wid;
    float mk = maskp[nidx];
    int row0 = bm * 64 + wid * 16 + lg * 4;
    u16* O2c = O2 + (size_t)c * ST;
    float ps[8], pq[8];
#pragma unroll
    for (int nc = 0; nc < 8; ++nc) {
        int col = nc * 16 + lr;
        float bb = bo[col];
        float sv = 0.f, qv = 0.f;
#pragma unroll
        for (int r = 0; r < 4; r++) {
            float v = acc[nc][r] + bb;
            if (mk != 0.f) O2c[(size_t)(row0 + r) * 128 + col] = f2bf(v);
            sv += v; qv += v * v;
        }
        ps[nc] = sv * mk; pq[nc] = qv * mk;
    }
#pragma unroll
    for (int nc = 0; nc < 8; ++nc) {
        ps[nc] += __shfl_xor(ps[nc], 16, 64); ps[nc] += __shfl_xor(ps[nc], 32, 64);
        pq[nc] += __shfl_xor(pq[nc], 16, 64); pq[nc] += __shfl_xor(pq[nc], 32, 64);
    }
    if (lane < 16) {
#pragma unroll
        for (int nc = 0; nc < 8; ++nc) {
            atomicAdd(&ssum[nc * 16 + lane], ps[nc]);
            atomicAdd(&ssq[nc * 16 + lane], pq[nc]);
        }
    }
    __syncthreads();
    if (tid < 128) { atomicAdd(&bnsum[c * 128 + tid], ssum[tid]); atomicAdd(&bnsq[c * 128 + tid], ssq[tid]); }
}

// ---------------- fused final GEMM over 8 experts, 512 threads (8 waves): grid 256 ----------
__global__ __launch_bounds__(512) void k_gemm_w1(const u16* __restrict__ O2, const u16* __restrict__ Xb,
        const u16* __restrict__ Wb, const float* __restrict__ eb1, const float* __restrict__ mb2,
        const float* __restrict__ eGamma, const float* __restrict__ mGamma,
        const float* __restrict__ eBeta, const float* __restrict__ mBeta,
        const float* __restrict__ comb8, const float* __restrict__ cnt8,
        const float* __restrict__ bnsum, const float* __restrict__ bnsq,
        float* __restrict__ out) {
    __shared__ u16 As[64 * 128];
    __shared__ u16 Bs[128 * 128];
    __shared__ float scall[8][128], shall[8][128];
    int tid = threadIdx.x; int bm = blockIdx.x;
    // BN scale/shift for all 8 experts
#pragma unroll
    for (int j = 0; j < 2; ++j) {
        int id = j * 512 + tid;
        int c = id >> 7, d = id & 127;
        float cnt = cnt8[c];
        float mean = bnsum[c * 128 + d] / cnt;
        float var = bnsq[c * 128 + d] / cnt - mean * mean;
        float rs = rsqrtf(var + EPSV);
        const float* ga = (c < 4) ? (eGamma + c * 128) : (mGamma + (c - 4) * 128);
        const float* be = (c < 4) ? (eBeta + c * 128) : (mBeta + (c - 4) * 128);
        float gg = ga[d];
        scall[c][d] = rs * gg;
        shall[c][d] = be[d] - mean * rs * gg;
    }
    __syncthreads();
    int lane = tid & 63, wid = tid >> 6, lr = lane & 15, lg = lane >> 4;
    int wm = wid & 3, wn = wid >> 2;        // 4 m-frags x 2 n-halves
    f32x4 acc[4] = {};
    const uint4* xsrc = (const uint4*)(Xb + (size_t)bm * 8192);
    for (int c = 0; c < 8; ++c) {
        float wc4[4];
        wc4[0] = comb8[c * NTOK + bm * 4];     wc4[1] = comb8[c * NTOK + bm * 4 + 1];
        wc4[2] = comb8[c * NTOK + bm * 4 + 2]; wc4[3] = comb8[c * NTOK + bm * 4 + 3];
        if (wc4[0] == 0.f && wc4[1] == 0.f && wc4[2] == 0.f && wc4[3] == 0.f) continue;
        int wsl = (c < 4) ? 16 + c : 36 + (c - 4);
        const u16* Wp = Wb + wsl * 16384;
        const uint4* osrc = (const uint4*)(O2 + (size_t)c * ST + (size_t)bm * 8192);
        // stage A = wc * (BN(O2) + x), bf16
#pragma unroll
        for (int it = 0; it < 2; ++it) {
            int qi = it * 512 + tid;
            int eo = qi * 8; int row = eo >> 7; int cb = eo & 127;
            float wc = wc4[row >> 4];
            uint4 ov = osrc[qi]; uint4 xv = xsrc[qi];
            float olo, ohi, xlo, xhi;
            uint4 hh;
            up2(ov.x, olo, ohi); up2(xv.x, xlo, xhi);
            hh.x = pack2(f2bf((olo * scall[c][cb] + shall[c][cb] + xlo) * wc),
                         f2bf((ohi * scall[c][cb + 1] + shall[c][cb + 1] + xhi) * wc));
            up2(ov.y, olo, ohi); up2(xv.y, xlo, xhi);
            hh.y = pack2(f2bf((olo * scall[c][cb + 2] + shall[c][cb + 2] + xlo) * wc),
                         f2bf((ohi * scall[c][cb + 3] + shall[c][cb + 3] + xhi) * wc));
            up2(ov.z, olo, ohi); up2(xv.z, xlo, xhi);
            hh.z = pack2(f2bf((olo * scall[c][cb + 4] + shall[c][cb + 4] + xlo) * wc),
                         f2bf((ohi * scall[c][cb + 5] + shall[c][cb + 5] + xhi) * wc));
            up2(ov.w, olo, ohi); up2(xv.w, xlo, xhi);
            hh.w = pack2(f2bf((olo * scall[c][cb + 6] + shall[c][cb + 6] + xlo) * wc),
                         f2bf((ohi * scall[c][cb + 7] + shall[c][cb + 7] + xhi) * wc));
            *(uint4*)((char*)As + ((eo * 2) ^ ((row & 7) << 4))) = hh;
        }
        const uint4* wsrc = (const uint4*)Wp;
#pragma unroll
        for (int it = 0; it < 4; ++it) {
            int qi = it * 512 + tid;
            uint4 v = wsrc[qi];
            int eo = qi * 8; int row = eo >> 7; int byte = eo * 2;
            *(uint4*)((char*)Bs + (byte ^ ((row & 7) << 4))) = v;
        }
        __syncthreads();
#pragma unroll
        for (int ks = 0; ks < 4; ++ks) {
            int kk = ks * 64 + lg * 16;
            int arow = wm * 16 + lr;
            short8 a = *(const short8*)((const char*)As + ((arow * 256 + kk) ^ ((arow & 7) << 4)));
#pragma unroll
            for (int nc = 0; nc < 4; ++nc) {
                int brow = wn * 64 + nc * 16 + lr;
                short8 b = *(const short8*)((const char*)Bs + ((brow * 256 + kk) ^ ((brow & 7) << 4)));
                acc[nc] = __builtin_amdgcn_mfma_f32_16x16x32_bf16(a, b, acc[nc], 0, 0, 0);
            }
        }
        __syncthreads();
    }
    // epilogue: add Sum_c wc*b1_c and write out once
    int nidx = bm * 4 + wm;
    int row0 = bm * 64 + wm * 16 + lg * 4;
    float wc8[8];
#pragma unroll
    for (int c = 0; c < 8; ++c) wc8[c] = comb8[c * NTOK + nidx];
#pragma unroll
    for (int nc = 0; nc < 4; ++nc) {
        int col = wn * 64 + nc * 16 + lr;
        float bias = 0.f;
#pragma unroll
        for (int c = 0; c < 8; ++c) {
            const float* b1 = (c < 4) ? (eb1 + c * 128) : (mb2 + (c - 4) * 128);
            bias += wc8[c] * b1[col];
        }
#pragma unroll
        for (int r = 0; r < 4; r++)
            out[(size_t)(row0 + r) * 128 + col] = acc[nc][r] + bias;
    }
}

extern "C" void kernel_launch(void* const* d_in, const int* in_sizes, int n_in,
                              void* d_out, int out_size, void* d_ws, size_t ws_size,
                              hipStream_t stream) {
    (void)in_sizes; (void)n_in; (void)ws_size; (void)out_size;
    const float* x    = (const float*)d_in[0];
    const float* mm   = (const float*)d_in[1];
    const float* tkv  = (const float*)d_in[2];
    const int*   idx  = (const int*)d_in[3];
    const int*   modi = (const int*)d_in[4];
    const float* Wr   = (const float*)d_in[5];
    const float* br   = (const float*)d_in[6];
    const float* eWq = (const float*)d_in[7],  *eWk = (const float*)d_in[8],  *eWv = (const float*)d_in[9];
    const float* eWo = (const float*)d_in[10], *eW1 = (const float*)d_in[11];
    const float* mWq = (const float*)d_in[12], *mWk = (const float*)d_in[13], *mWv = (const float*)d_in[14];
    const float* mWo = (const float*)d_in[15], *mW2 = (const float*)d_in[16];
    const float* ebq = (const float*)d_in[17], *ebk = (const float*)d_in[18], *ebv = (const float*)d_in[19];
    const float* ebo = (const float*)d_in[20], *eBeta = (const float*)d_in[21], *eb1 = (const float*)d_in[22];
    const float* mbq = (const float*)d_in[23], *mbk = (const float*)d_in[24], *mbv = (const float*)d_in[25];
    const float* mbo = (const float*)d_in[26], *mBeta = (const float*)d_in[27], *mb2 = (const float*)d_in[28];
    const float* eGamma = (const float*)d_in[29], *mGamma = (const float*)d_in[30];
    float* out = (float*)d_out;

    char* wsb = (char*)d_ws;
    const size_t MB = 1024 * 1024;
    u16* Xb  = (u16*)wsb;                       // 0..4 MB
    u16* Wb  = (u16*)(wsb + 4 * MB);            // 4..5.3 MB (40 x 16384 bf16)
    u16* Qb  = (u16*)(wsb + 8 * MB);            // 8..40 MB  (attn O in-place)
    u16* KVb = (u16*)(wsb + 40 * MB);           // 40..104 MB (8 x 8MB K|V interleaved)
    u16* O2  = (u16*)(wsb + 104 * MB);          // 104..136 MB (bf16)
    float* logits = (float*)(wsb + 136 * MB);
    float* comb8 = logits + 4096;               // [8][1024]
    float* mask8 = comb8 + 8192;                // [8][1024]
    float* cnt8  = mask8 + 8192;                // [8]
    float* bnsum = cnt8 + 16;                   // [8][128]
    float* bnsq  = bnsum + 1024;                // [8][128]

    k_prep<<<1360, 256, 0, stream>>>(x, eWq, eWk, eWv, eWo, eW1, mWq, mWk, mWv, mWo, mW2,
                                     mm, Wr, br, Xb, Wb, logits);
    k_route<<<1, 1024, 0, stream>>>(logits, modi, mask8, comb8, cnt8, bnsum, bnsq,
                                    out + (size_t)TT * DD);
    k_gemm_qkv<<<dim3(256, 8), 256, 0, stream>>>(Xb, Wb, ebq, mbq, mask8, Qb, KVb);
    k_attn<<<4096, 256, 0, stream>>>(Qb, KVb, tkv, idx, ebk, ebv, mbk, mbv, mask8, Qb);
    k_gemm_o<<<dim3(256, 8), 256, 0, stream>>>(Qb, Wb, ebo, mbo, O2, mask8, bnsum, bnsq);
    k_gemm_w1<<<256, 512, 0, stream>>>(O2, Xb, Wb, eb1, mb2, eGamma, mGamma, eBeta, mBeta,
                                       comb8, cnt8, bnsum, bnsq, out);
}